// Round 9
// baseline (12.310 us; speedup 1.0000x reference)
//
#include <hip/hip_runtime.h>
#include <math.h>

// Local banded attention: B=2, L=2048, H=8, E=D=64, window w=7 (band=15).
// R8: query PAIRING — each 16-lane group handles 2 consecutive queries over
// their 16-row union band; one ds_read_b128 feeds both queries (DS instr
// per wave 65 -> 37 vs R3). Geometry = R3 (proven): block 512 = 8 waves =
// 64 queries of one (b,h); K+V in XOR-swizzled LDS (40KB), single barrier.
// Lane: group g = lane>>4 (2 queries), c4 = lane&15 (4 channels, 1 float4).
// Dot reduce = 4 DPP adds over 16 lanes (xor1, xor2, half-mirror, mirror).

constexpr int L_DIM = 2048;
constexpr int H_DIM = 8;
constexpr int E_DIM = 64;
constexpr int W = 7;
constexpr int NU = 16;               // union band rows per query pair
constexpr int TQ = 64;               // queries per block
constexpr int HALO = 8;
constexpr int ROWS = TQ + 2 * HALO;  // 80 staged rows per matrix

template <int CTRL>
__device__ __forceinline__ float dpp_add(float s) {
  int t = __builtin_amdgcn_mov_dpp(__builtin_bit_cast(int, s), CTRL, 0xF, 0xF, true);
  return s + __builtin_bit_cast(float, t);
}

__global__ __launch_bounds__(512, 4) void local_attn_kernel(
    const float* __restrict__ q,
    const float* __restrict__ k,
    const float* __restrict__ v,
    float* __restrict__ out) {
  __shared__ float ks[ROWS * E_DIM];  // 20 KB
  __shared__ float vs[ROWS * E_DIM];  // 20 KB

  // XCD-aware swizzle (grid = 512, divisible by 8)
  const int cpx = gridDim.x >> 3;
  const int bid = (blockIdx.x & 7) * cpx + (blockIdx.x >> 3);

  const int tile = bid & (L_DIM / TQ - 1);  // 32 tiles per (b,h)
  const int bh = bid >> 5;
  const int h = bh & (H_DIM - 1);
  const int b = bh >> 3;
  const int l0 = tile * TQ;

  const int tid = threadIdx.x;
  const int wv = tid >> 6;    // wave [0,8)
  const int lane = tid & 63;
  const int g = lane >> 4;    // query pair within wave [0,4)
  const int c4 = lane & 15;   // 16B column group -> channels c4*4..c4*4+3

  const size_t bhb = (size_t)b * L_DIM * H_DIM + h;

  // ---- stage K and V: 40 chunks of 4 rows x 64 floats; wave takes 5 ----
  const int rsub = lane >> 4;
#pragma unroll
  for (int t = 0; t < 5; ++t) {
    const int ch = wv + t * 8;           // 0..39
    const int m = (ch >= 20) ? 1 : 0;    // 0: K, 1: V
    const int cc = ch - m * 20;
    const int rl = cc * 4 + rsub;        // LDS row 0..79
    int rg = l0 - HALO + rl;
    rg = rg < 0 ? 0 : (rg > L_DIM - 1 ? L_DIM - 1 : rg);
    const float4 val =
        *(const float4*)((m ? v : k) + ((bhb + (size_t)rg * H_DIM) << 6) + c4 * 4);
    *(float4*)&((m ? vs : ks)[(rl * 16 + (c4 ^ (rl & 7))) * 4]) = val;
  }

  // ---- Q -> regs: two queries per group (overlaps staging) ----
  const int lA_loc = wv * 8 + 2 * g;   // 0..62 even
  const int lA = l0 + lA_loc;          // query A; B = lA + 1
  const float* qpA = q + ((bhb + (size_t)lA * H_DIM) << 6) + c4 * 4;
  float4 qA = *(const float4*)qpA;
  float4 qB = *(const float4*)(qpA + (H_DIM << 6));  // next l, same h
  const float scale = 0.125f;  // 1/sqrt(64)
  qA.x *= scale; qA.y *= scale; qA.z *= scale; qA.w *= scale;
  qB.x *= scale; qB.y *= scale; qB.z *= scale; qB.w *= scale;

  __syncthreads();

  // ---- scores over the pair's 16-row union band ----
  // row i: global key kk = lA - 7 + i; LDS row rl = lA_loc + 1 + i (1..78)
  // valid for A iff i<=14 (band pos i), for B iff i>=1 (band pos i-1).
  const int base_rl = lA_loc + 1;
  float scA[NU], scB[NU];
#pragma unroll
  for (int i = 0; i < NU; ++i) {
    const int rl = base_rl + i;
    const float4 k0 = *(const float4*)&ks[(rl * 16 + (c4 ^ (rl & 7))) * 4];
    float sA = qA.x * k0.x + qA.y * k0.y + qA.z * k0.z + qA.w * k0.w;
    float sB = qB.x * k0.x + qB.y * k0.y + qB.z * k0.z + qB.w * k0.w;
    sA = dpp_add<0xB1>(sA);   sB = dpp_add<0xB1>(sB);    // xor 1
    sA = dpp_add<0x4E>(sA);   sB = dpp_add<0x4E>(sB);    // xor 2
    sA = dpp_add<0x141>(sA);  sB = dpp_add<0x141>(sB);   // xor 4 (uniform quads)
    sA = dpp_add<0x140>(sA);  sB = dpp_add<0x140>(sB);   // xor 8 (uniform octets)
    const int kk = lA - W + i;
    const bool inr = (unsigned)kk < (unsigned)L_DIM;
    scA[i] = (inr && i < 15) ? sA : -INFINITY;
    scB[i] = (inr && i >= 1) ? sB : -INFINITY;
  }

  // ---- softmax for both queries ----
  float mA = scA[0], mB = scB[1];
#pragma unroll
  for (int i = 1; i < NU; ++i) mA = fmaxf(mA, scA[i]);
#pragma unroll
  for (int i = 2; i < NU; ++i) mB = fmaxf(mB, scB[i]);
  float dA = 0.0f, dB = 0.0f;
#pragma unroll
  for (int i = 0; i < NU; ++i) {
    scA[i] = __expf(scA[i] - mA);
    dA += scA[i];
    scB[i] = __expf(scB[i] - mB);
    dB += scB[i];
  }
  const float invA = __builtin_amdgcn_rcpf(dA);
  const float invB = __builtin_amdgcn_rcpf(dB);

  // ---- PV: one V-row read feeds both queries ----
  float4 aA = {0.f, 0.f, 0.f, 0.f};
  float4 aB = {0.f, 0.f, 0.f, 0.f};
#pragma unroll
  for (int i = 0; i < NU; ++i) {
    const int rl = base_rl + i;
    const float4 v0 = *(const float4*)&vs[(rl * 16 + (c4 ^ (rl & 7))) * 4];
    const float pA = scA[i];
    const float pB = scB[i];
    aA.x += pA * v0.x; aA.y += pA * v0.y; aA.z += pA * v0.z; aA.w += pA * v0.w;
    aB.x += pB * v0.x; aB.y += pB * v0.y; aB.z += pB * v0.z; aB.w += pB * v0.w;
  }

  float* opA = out + ((bhb + (size_t)lA * H_DIM) << 6) + c4 * 4;
  aA.x *= invA; aA.y *= invA; aA.z *= invA; aA.w *= invA;
  aB.x *= invB; aB.y *= invB; aB.z *= invB; aB.w *= invB;
  *(float4*)opA = aA;
  *(float4*)(opA + (H_DIM << 6)) = aB;
}

extern "C" void kernel_launch(void* const* d_in, const int* in_sizes, int n_in,
                              void* d_out, int out_size, void* d_ws, size_t ws_size,
                              hipStream_t stream) {
  const float* q = (const float*)d_in[0];
  const float* k = (const float*)d_in[1];
  const float* v = (const float*)d_in[2];
  float* out = (float*)d_out;

  const int B = in_sizes[0] / (L_DIM * H_DIM * E_DIM);  // = 2
  const int blocks = B * H_DIM * (L_DIM / TQ);          // 512

  local_attn_kernel<<<blocks, 512, 0, stream>>>(q, k, v, out);
}